// Round 10
// baseline (391.756 us; speedup 1.0000x reference)
//
#include <hip/hip_runtime.h>
#include <stdint.h>

typedef __bf16 bf16;
typedef __bf16 bf16x2 __attribute__((ext_vector_type(2)));
typedef __bf16 bf16x4 __attribute__((ext_vector_type(4)));
typedef __bf16 bf16x8 __attribute__((ext_vector_type(8)));
typedef float  fx2    __attribute__((ext_vector_type(2)));
typedef float  fx4    __attribute__((ext_vector_type(4)));

#define MFMA16(a, b, c) __builtin_amdgcn_mfma_f32_16x16x32_bf16((a), (b), (c), 0, 0, 0)

// B=4, N=2048, E=768, H=8, D=96; M = B*N = 8192. User tensors fp32, out fp32.

// ---------------------------------------------------------------------------
// Barrier WITHOUT the vmem drain (lgkmcnt(0) only). Keeps global_load_lds
// DMA in flight across barriers. 0xC07F = vmcnt 63 (nowait), exp 7, lgkm 0.
// ---------------------------------------------------------------------------
__device__ __forceinline__ void barrier_nodrain() {
  __asm__ __volatile__("" ::: "memory");
  __builtin_amdgcn_s_waitcnt(0xC07F);
  __builtin_amdgcn_s_barrier();
  __asm__ __volatile__("" ::: "memory");
}

// Counted vmem waits. Encoding: vmcnt[3:0], lgkm[11:8]=F nowait, exp[6:4]=7.
__device__ __forceinline__ void wait_vm3() {
  __asm__ __volatile__("" ::: "memory");
  __builtin_amdgcn_s_waitcnt(0x0F73);
  __asm__ __volatile__("" ::: "memory");
}
// lgkmcnt(0) only (LDS reads retired; region safe to overwrite).
__device__ __forceinline__ void wait_lgkm0() {
  __asm__ __volatile__("" ::: "memory");
  __builtin_amdgcn_s_waitcnt(0xC07F);
  __asm__ __volatile__("" ::: "memory");
}

// DMA 16 B/lane global -> LDS (dest = wave-uniform base + lane*16, m104).
__device__ __forceinline__ void gload_lds16(const void* g, void* l) {
  __builtin_amdgcn_global_load_lds(
      (const __attribute__((address_space(1))) void*)g,
      (__attribute__((address_space(3))) void*)l, 16, 0, 0);
}

// ---------------------------------------------------------------------------
// x (fp32) -> bf16, 4 elems/thread.
// ---------------------------------------------------------------------------
__global__ __launch_bounds__(256)
void cvt_x_kernel(const float* __restrict__ x, bf16* __restrict__ xb) {
  const int i = (blockIdx.x * 256 + threadIdx.x) * 4;
  float4 v = *(const float4*)&x[i];
  bf16x4 o;
  o[0] = (bf16)v.x; o[1] = (bf16)v.y; o[2] = (bf16)v.z; o[3] = (bf16)v.w;
  *(bf16x4*)&xb[i] = o;
}

// ---------------------------------------------------------------------------
// Fused QKV GEMM (R17 structure, proven): A DMA double-buffered, B coalesced
// reg-staged. R20: K/V written in 16-k-granular staging tiles (1536 elems =
// 3 KB per (b,h,kt16)):
//   K: [b][h][kt16][u=d/8][k16][d%8]
//   V: [b][h][kt16][ku=(k%16)/8][d96][k%8]
// ---------------------------------------------------------------------------
__global__ __launch_bounds__(256)
void gemm_qkv(const bf16* __restrict__ A,
              const float* __restrict__ Wq, const float* __restrict__ Wk,
              const float* __restrict__ Wv,
              const float* __restrict__ bq, const float* __restrict__ bk,
              const float* __restrict__ bv,
              bf16* __restrict__ Qo, bf16* __restrict__ Ka,
              bf16* __restrict__ Va) {
  constexpr int K = 768;
  __shared__ __align__(16) bf16 As[2][128 * 32];
  __shared__ __align__(16) bf16 Bs[128 * 32];

  const int tid  = threadIdx.x;
  const int wave = tid >> 6;
  const int lane = tid & 63;
  const int l15  = lane & 15;
  const int q4   = lane >> 4;
  const int wr   = wave >> 1;
  const int wc   = wave & 1;
  const int sel  = blockIdx.x / 6;
  const int cb0  = (blockIdx.x % 6) * 128;
  const int rb0  = blockIdx.y * 128;

  const float* W   = (sel == 0) ? Wq : (sel == 1) ? Wk : Wv;
  const float* bia = (sel == 0) ? bq : (sel == 1) ? bk : bv;

  const int ar0 = tid >> 2,         akc0 = (tid & 3) << 3;
  const int ar1 = ar0 + 64,         akc1 = akc0;

  fx4 acc[4][4];
#pragma unroll
  for (int i = 0; i < 4; i++)
#pragma unroll
    for (int j = 0; j < 4; j++) acc[i][j] = (fx4){0.f, 0.f, 0.f, 0.f};

  gload_lds16(&A[(size_t)(rb0 + ar0) * K + akc0], &As[0][wave * 512]);
  gload_lds16(&A[(size_t)(rb0 + ar1) * K + akc1], &As[0][(wave + 4) * 512]);

  int cur = 0;
  for (int k0 = 0; k0 < K; k0 += 32, cur ^= 1) {
    const float* wp0 = W + (size_t)(cb0 + ar0) * K + k0 + akc0;
    const float* wp1 = W + (size_t)(cb0 + ar1) * K + k0 + akc1;
    const float4 b0a = *(const float4*)wp0;
    const float4 b0b = *(const float4*)(wp0 + 4);
    const float4 b1a = *(const float4*)wp1;
    const float4 b1b = *(const float4*)(wp1 + 4);
    __asm__ __volatile__("" ::: "memory");

    const int kn = (k0 + 32 < K) ? k0 + 32 : k0;
    gload_lds16(&A[(size_t)(rb0 + ar0) * K + kn + akc0],
                &As[cur ^ 1][wave * 512]);
    gload_lds16(&A[(size_t)(rb0 + ar1) * K + kn + akc1],
                &As[cur ^ 1][(wave + 4) * 512]);
    __asm__ __volatile__("" ::: "memory");

    bf16x8 pb0, pb1;
    pb0[0] = (bf16)b0a.x; pb0[1] = (bf16)b0a.y;
    pb0[2] = (bf16)b0a.z; pb0[3] = (bf16)b0a.w;
    pb0[4] = (bf16)b0b.x; pb0[5] = (bf16)b0b.y;
    pb0[6] = (bf16)b0b.z; pb0[7] = (bf16)b0b.w;
    pb1[0] = (bf16)b1a.x; pb1[1] = (bf16)b1a.y;
    pb1[2] = (bf16)b1a.z; pb1[3] = (bf16)b1a.w;
    pb1[4] = (bf16)b1b.x; pb1[5] = (bf16)b1b.y;
    pb1[6] = (bf16)b1b.z; pb1[7] = (bf16)b1b.w;
    *(bf16x8*)&Bs[ar0 * 32 + akc0] = pb0;
    *(bf16x8*)&Bs[ar1 * 32 + akc1] = pb1;

    barrier_nodrain();

    bf16x8 a[4], b[4];
#pragma unroll
    for (int i = 0; i < 4; i++)
      a[i] = *(const bf16x8*)&As[cur][(wr * 64 + i * 16 + l15) * 32 + q4 * 8];
#pragma unroll
    for (int j = 0; j < 4; j++)
      b[j] = *(const bf16x8*)&Bs[(wc * 64 + j * 16 + l15) * 32 + q4 * 8];
#pragma unroll
    for (int i = 0; i < 4; i++)
#pragma unroll
      for (int j = 0; j < 4; j++)
        acc[i][j] = MFMA16(a[i], b[j], acc[i][j]);

    barrier_nodrain();
  }

  const int cb = cb0 + wc * 64;
  const int rb = rb0 + wr * 64;
#pragma unroll
  for (int j = 0; j < 4; j++) {
    const int o  = cb + j * 16 + l15;
    const float bj = bia[o];
    const int hh = o / 96;
    const int dd = o - hh * 96;
#pragma unroll
    for (int i = 0; i < 4; i++) {
      const int r0 = rb + i * 16 + q4 * 4;
      if (sel == 2) {
        // V: flat = tile16*1536 + ((k%16)/8)*768 + d*8 + k%8 (4 consec k)
        const int bb = r0 >> 11;
        const int n2 = r0 & 2047;
        const size_t flat =
            ((size_t)((bb * 8 + hh) * 128 + (n2 >> 4))) * 1536 +
            ((n2 >> 3) & 1) * 768 + dd * 8 + (n2 & 7);
        bf16x4 pk;
#pragma unroll
        for (int r = 0; r < 4; r++) pk[r] = (bf16)(acc[i][j][r] + bj);
        *(bf16x4*)&Va[flat] = pk;
      } else if (sel == 1) {
        // K: flat = tile16*1536 + (d/8)*128 + (k%16)*8 + d%8
        const int u  = dd >> 3;
        const int de = dd & 7;
#pragma unroll
        for (int r = 0; r < 4; r++) {
          const int n  = r0 + r;
          const int bb = n >> 11;
          const int n2 = n & 2047;
          const size_t flat =
              ((size_t)((bb * 8 + hh) * 128 + (n2 >> 4))) * 1536 +
              u * 128 + (n2 & 15) * 8 + de;
          Ka[flat] = (bf16)(acc[i][j][r] + bj);
        }
      } else {
#pragma unroll
        for (int r = 0; r < 4; r++)
          Qo[(size_t)(r0 + r) * 768 + o] = (bf16)(acc[i][j][r] + bj);
      }
    }
  }
}

// ---------------------------------------------------------------------------
// Output projection: out[M,768] fp32 = AO bf16 @ Wo^T + bo (R17, proven).
// ---------------------------------------------------------------------------
__global__ __launch_bounds__(256)
void gemm_o(const bf16* __restrict__ A, const float* __restrict__ W,
            const float* __restrict__ bias, float* __restrict__ C) {
  constexpr int K = 768;
  __shared__ __align__(16) bf16 As[2][128 * 32];
  __shared__ __align__(16) bf16 Bs[128 * 32];

  const int tid  = threadIdx.x;
  const int wave = tid >> 6;
  const int lane = tid & 63;
  const int l15  = lane & 15;
  const int q4   = lane >> 4;
  const int wr   = wave >> 1;
  const int wc   = wave & 1;
  const int rb0  = blockIdx.y * 128;
  const int cb0  = blockIdx.x * 128;

  const int ar0 = tid >> 2,         akc0 = (tid & 3) << 3;
  const int ar1 = ar0 + 64,         akc1 = akc0;

  fx4 acc[4][4];
#pragma unroll
  for (int i = 0; i < 4; i++)
#pragma unroll
    for (int j = 0; j < 4; j++) acc[i][j] = (fx4){0.f, 0.f, 0.f, 0.f};

  gload_lds16(&A[(size_t)(rb0 + ar0) * K + akc0], &As[0][wave * 512]);
  gload_lds16(&A[(size_t)(rb0 + ar1) * K + akc1], &As[0][(wave + 4) * 512]);

  int cur = 0;
  for (int k0 = 0; k0 < K; k0 += 32, cur ^= 1) {
    const float* wp0 = W + (size_t)(cb0 + ar0) * K + k0 + akc0;
    const float* wp1 = W + (size_t)(cb0 + ar1) * K + k0 + akc1;
    const float4 b0a = *(const float4*)wp0;
    const float4 b0b = *(const float4*)(wp0 + 4);
    const float4 b1a = *(const float4*)wp1;
    const float4 b1b = *(const float4*)(wp1 + 4);
    __asm__ __volatile__("" ::: "memory");

    const int kn = (k0 + 32 < K) ? k0 + 32 : k0;
    gload_lds16(&A[(size_t)(rb0 + ar0) * K + kn + akc0],
                &As[cur ^ 1][wave * 512]);
    gload_lds16(&A[(size_t)(rb0 + ar1) * K + kn + akc1],
                &As[cur ^ 1][(wave + 4) * 512]);
    __asm__ __volatile__("" ::: "memory");

    bf16x8 pb0, pb1;
    pb0[0] = (bf16)b0a.x; pb0[1] = (bf16)b0a.y;
    pb0[2] = (bf16)b0a.z; pb0[3] = (bf16)b0a.w;
    pb0[4] = (bf16)b0b.x; pb0[5] = (bf16)b0b.y;
    pb0[6] = (bf16)b0b.z; pb0[7] = (bf16)b0b.w;
    pb1[0] = (bf16)b1a.x; pb1[1] = (bf16)b1a.y;
    pb1[2] = (bf16)b1a.z; pb1[3] = (bf16)b1a.w;
    pb1[4] = (bf16)b1b.x; pb1[5] = (bf16)b1b.y;
    pb1[6] = (bf16)b1b.z; pb1[7] = (bf16)b1b.w;
    *(bf16x8*)&Bs[ar0 * 32 + akc0] = pb0;
    *(bf16x8*)&Bs[ar1 * 32 + akc1] = pb1;

    barrier_nodrain();

    bf16x8 a[4], b[4];
#pragma unroll
    for (int i = 0; i < 4; i++)
      a[i] = *(const bf16x8*)&As[cur][(wr * 64 + i * 16 + l15) * 32 + q4 * 8];
#pragma unroll
    for (int j = 0; j < 4; j++)
      b[j] = *(const bf16x8*)&Bs[(wc * 64 + j * 16 + l15) * 32 + q4 * 8];
#pragma unroll
    for (int i = 0; i < 4; i++)
#pragma unroll
      for (int j = 0; j < 4; j++)
        acc[i][j] = MFMA16(a[i], b[j], acc[i][j]);

    barrier_nodrain();
  }

  const int cb = cb0 + wc * 64;
  const int rb = rb0 + wr * 64;
#pragma unroll
  for (int j = 0; j < 4; j++) {
    const int o  = cb + j * 16 + l15;
    const float bj = bias[o];
#pragma unroll
    for (int i = 0; i < 4; i++) {
      const int r0 = rb + i * 16 + q4 * 4;
#pragma unroll
      for (int r = 0; r < 4; r++)
        C[(size_t)(r0 + r) * 768 + o] = acc[i][j][r] + bj;
    }
  }
}

// ---------------------------------------------------------------------------
// Attention, softmax over HEADS (dim=1), / sqrt(768).
// R20: 2 blocks/CU. R15-R19 post-mortems: every in-structure tweak moved
// <=5%; 5240 cyc/iter vs ~1100 serial-chain estimate => barrier/wait skew
// of 8 lockstep waves with ONE block resident is the structural cost.
// Changes:
//  - 16 q-rows x 16-k tiles (128 iters). LDS 63.7 KB => 2 blocks fit in
//    160 KB. Grid 512 = 2 independent barrier groups per CU.
//  - PV keeps proven 16x16x32 MFMA with half-filled frags: lanes q4>=2
//    (k>=16) carry explicit zeros in BOTH A and B (0x0=0, no NaN path).
//  - K re-tiled to 3 KB DMA tiles [u12][k16][8]; V to [ku2][d96][8].
//    3 loads/tile => counted wait vm3.
//  - __launch_bounds__(512,2): deliberate 128-VGPR cap (R11 calibration)
//    to guarantee 2-block placement; est. need ~100; K/V are DMA (0 VGPR).
//  - XCD swizzle (assume xcd=bid%8): b=(bid&7)>>1 => each XCD pair serves
//    one batch b; staging window stays L2-local. Bijective remap.
// Banking: Ebuf stride 132 (2-way), Pbuf pad 24 (2-way), K/V frags <=4-way.
// Go/no-go: OccupancyPercent ~40-48%. If ~22%, co-residency lever is dead
// => revert attn to R19, pivot to GEMM 8-phase.
// ---------------------------------------------------------------------------
__global__ __launch_bounds__(512, 2)
void attn_kernel(const bf16* Q, const bf16* __restrict__ Ka,
                 const bf16* __restrict__ Va, bf16* AO) {
  __shared__ __align__(16) bf16  Kbuf[8 * 1536];    // [h][u12][k16][8] 24 KB
  __shared__ __align__(16) bf16  Vbuf[8 * 1536];    // [h][ku2][d96][8] 24 KB
  __shared__ __align__(16) float Ebuf[16 * 132];    // [q][h*16+k]   8.25 KB
  __shared__ __align__(16) bf16  Pbuf[8 * 16 * 24]; // [h][q][k pad24]  6 KB

  const int tid  = threadIdx.x;
  const int h    = tid >> 6;
  const int lane = tid & 63;
  const int l15  = lane & 15;
  const int q4   = lane >> 4;
  const int bid  = blockIdx.x;
  const int b    = (bid & 7) >> 1;                 // XCD pair -> batch
  const int qt   = ((bid & 1) << 6) | (bid >> 3);  // 0..127, bijective
  const int qrow0 = b * 2048 + qt * 16;

  // Persistent Q fragments (B-operand of swapped QK^T): col q=l15, d chunks.
  bf16x8 aq[3];
#pragma unroll
  for (int c = 0; c < 3; c++)
    aq[c] = *(const bf16x8*)
        &Q[(size_t)(qrow0 + l15) * 768 + h * 96 + c * 32 + q4 * 8];

  fx4 o[6];
#pragma unroll
  for (int j = 0; j < 6; j++) o[j] = (fx4){0.f, 0.f, 0.f, 0.f};

  const bf16* Kt0 = Ka + (size_t)(b * 8 + h) * 128 * 1536;
  const bf16* Vt0 = Va + (size_t)(b * 8 + h) * 128 * 1536;
  bf16* Kl = &Kbuf[h * 1536];
  bf16* Vl = &Vbuf[h * 1536];

  auto stageK = [&](int kt) {
    const bf16* src = Kt0 + (size_t)kt * 1536 + lane * 8;
#pragma unroll
    for (int t = 0; t < 3; t++)
      gload_lds16(src + t * 512, Kl + t * 512);
  };
  auto stageV = [&](int kt) {
    const bf16* src = Vt0 + (size_t)kt * 1536 + lane * 8;
#pragma unroll
    for (int t = 0; t < 3; t++)
      gload_lds16(src + t * 512, Vl + t * 512);
  };

  stageK(0);
  stageV(0);

  for (int kt = 0; kt < 128; kt++) {
    const int kn = (kt + 1 < 128) ? kt + 1 : 127;

    // --- K(kt) ready? (V(kt)'s 3 loads stay outstanding) ---
    wait_vm3();

    // K frags (A operand): rows k=l15, d = c*32+q4*8 -> u = c*4+q4.
    bf16x8 bk[3];
#pragma unroll
    for (int c = 0; c < 3; c++)
      bk[c] = *(const bf16x8*)&Kl[(c * 4 + q4) * 128 + l15 * 8];

    wait_lgkm0();
    stageK(kn);

    // E^T = K Q^T: output col=q=l15, row=k=q4*4+r (4 consecutive k).
    fx4 e2 = (fx4){0.f, 0.f, 0.f, 0.f};
    __builtin_amdgcn_s_setprio(1);
#pragma unroll
    for (int c = 0; c < 3; c++)
      e2 = MFMA16(bk[c], aq[c], e2);
    __builtin_amdgcn_s_setprio(0);

    // Vectorized scatter: one b128 -> Ebuf[q*132 + h*16 + k0].
    *(fx4*)&Ebuf[l15 * 132 + h * 16 + q4 * 4] = e2;
    barrier_nodrain();

    // Softmax over heads. 256 (q,k) pairs, waves 0-3 (1 pair/thread).
    if (tid < 256) {
      const int q = tid & 15, k = tid >> 4;
      const float* row = &Ebuf[q * 132 + k];
      float v[8];
#pragma unroll
      for (int hh = 0; hh < 8; hh++) v[hh] = row[hh * 16];
      float m = v[0];
#pragma unroll
      for (int hh = 1; hh < 8; hh++) m = fmaxf(m, v[hh]);
      float sm = 0.f;
#pragma unroll
      for (int hh = 0; hh < 8; hh++) { v[hh] = __expf(v[hh] - m); sm += v[hh]; }
      const float inv = 1.0f / (sm * 27.712812921102035f);  // / sqrt(768)
#pragma unroll
      for (int hh = 0; hh < 8; hh++)
        Pbuf[hh * 384 + q * 24 + k] = (bf16)(v[hh] * inv);
    }
    barrier_nodrain();

    // --- V(kt) ready? (K(kn)'s 3 loads stay outstanding) ---
    wait_vm3();

    // Half-filled frags for 16x16x32 PV: lanes q4<2 hold k=0..15 data,
    // lanes q4>=2 hold zeros in BOTH operands (0*0 contributions).
    bf16x8 bv[6], ap;
    if (q4 < 2) {
#pragma unroll
      for (int j2 = 0; j2 < 6; j2++)
        bv[j2] = *(const bf16x8*)&Vl[q4 * 768 + (j2 * 16 + l15) * 8];
      ap = *(const bf16x8*)&Pbuf[h * 384 + l15 * 24 + q4 * 8];
    } else {
      bf16x8 z;
#pragma unroll
      for (int t = 0; t < 8; t++) z[t] = (bf16)0.f;
#pragma unroll
      for (int j2 = 0; j2 < 6; j2++) bv[j2] = z;
      ap = z;
    }

    wait_lgkm0();
    stageV(kn);

    // O += P @ V.
    __builtin_amdgcn_s_setprio(1);
#pragma unroll
    for (int j2 = 0; j2 < 6; j2++)
      o[j2] = MFMA16(ap, bv[j2], o[j2]);
    __builtin_amdgcn_s_setprio(0);
  }

  // Drain outstanding DMA before exit/stores.
  __builtin_amdgcn_s_waitcnt(0x0070);

  // Write AO[qrow0 + q][h*96 + d]; o layout: row q=q4*4+r, col d=j2*16+l15.
#pragma unroll
  for (int j2 = 0; j2 < 6; j2++)
#pragma unroll
    for (int r = 0; r < 4; r++)
      AO[(size_t)(qrow0 + q4 * 4 + r) * 768 + h * 96 + j2 * 16 + l15] =
          (bf16)(o[j2][r]);
}

// ---------------------------------------------------------------------------
// Memory plan: d_out = xb + Ka (both dead before gemm_o overwrites d_out).
// ws = Q + Va (25.2 MB). AO aliases Q. Ka/Va = MN elems (32*128*1536).
// ---------------------------------------------------------------------------
extern "C" void kernel_launch(void* const* d_in, const int* in_sizes, int n_in,
                              void* d_out, int out_size, void* d_ws,
                              size_t ws_size, hipStream_t stream) {
  const float* x  = (const float*)d_in[0];
  const float* Wq = (const float*)d_in[1];
  const float* bq = (const float*)d_in[2];
  const float* Wk = (const float*)d_in[3];
  const float* bk = (const float*)d_in[4];
  const float* Wv = (const float*)d_in[5];
  const float* bv = (const float*)d_in[6];
  const float* Wo = (const float*)d_in[7];
  const float* bo = (const float*)d_in[8];

  const size_t MN = (size_t)8192 * 768;
  bf16* xb = (bf16*)d_out;
  bf16* Ka = xb + MN;
  bf16* Q  = (bf16*)d_ws;
  bf16* Va = Q + MN;
  bf16* AO = Q;  // aliases Q

  cvt_x_kernel<<<6144, 256, 0, stream>>>(x, xb);
  dim3 qkvgrid(18, 64);
  gemm_qkv<<<qkvgrid, 256, 0, stream>>>(xb, Wq, Wk, Wv, bq, bk, bv, Q, Ka, Va);
  attn_kernel<<<512, 512, 0, stream>>>(Q, Ka, Va, AO);
  dim3 ogrid(6, 64);
  gemm_o<<<ogrid, 256, 0, stream>>>(AO, Wo, bo, (float*)d_out);
}

// Round 11
// 290.570 us; speedup vs baseline: 1.3482x; 1.3482x over previous
//
#include <hip/hip_runtime.h>
#include <stdint.h>

typedef __bf16 bf16;
typedef __bf16 bf16x2 __attribute__((ext_vector_type(2)));
typedef __bf16 bf16x4 __attribute__((ext_vector_type(4)));
typedef __bf16 bf16x8 __attribute__((ext_vector_type(8)));
typedef float  fx2    __attribute__((ext_vector_type(2)));
typedef float  fx4    __attribute__((ext_vector_type(4)));

#define MFMA16(a, b, c) __builtin_amdgcn_mfma_f32_16x16x32_bf16((a), (b), (c), 0, 0, 0)

// B=4, N=2048, E=768, H=8, D=96; M = B*N = 8192. User tensors fp32, out fp32.

// ---------------------------------------------------------------------------
// Barrier WITHOUT the vmem drain (lgkmcnt(0) only).
// ---------------------------------------------------------------------------
__device__ __forceinline__ void barrier_nodrain() {
  __asm__ __volatile__("" ::: "memory");
  __builtin_amdgcn_s_waitcnt(0xC07F);
  __builtin_amdgcn_s_barrier();
  __asm__ __volatile__("" ::: "memory");
}

// Counted vmem waits: vmcnt[3:0] | exp=7 nowait | lgkm=0xF nowait.
__device__ __forceinline__ void wait_vm6() {
  __asm__ __volatile__("" ::: "memory");
  __builtin_amdgcn_s_waitcnt(0x0F76);
  __asm__ __volatile__("" ::: "memory");
}
__device__ __forceinline__ void wait_vm4() {
  __asm__ __volatile__("" ::: "memory");
  __builtin_amdgcn_s_waitcnt(0x0F74);
  __asm__ __volatile__("" ::: "memory");
}
__device__ __forceinline__ void wait_lgkm0() {
  __asm__ __volatile__("" ::: "memory");
  __builtin_amdgcn_s_waitcnt(0xC07F);
  __asm__ __volatile__("" ::: "memory");
}

// DMA 16 B/lane global -> LDS (dest = wave-uniform base + lane*16, m104).
__device__ __forceinline__ void gload_lds16(const void* g, void* l) {
  __builtin_amdgcn_global_load_lds(
      (const __attribute__((address_space(1))) void*)g,
      (__attribute__((address_space(3))) void*)l, 16, 0, 0);
}

// ---------------------------------------------------------------------------
// x (fp32) -> bf16, 4 elems/thread.
// ---------------------------------------------------------------------------
__global__ __launch_bounds__(256)
void cvt_x_kernel(const float* __restrict__ x, bf16* __restrict__ xb) {
  const int i = (blockIdx.x * 256 + threadIdx.x) * 4;
  float4 v = *(const float4*)&x[i];
  bf16x4 o;
  o[0] = (bf16)v.x; o[1] = (bf16)v.y; o[2] = (bf16)v.z; o[3] = (bf16)v.w;
  *(bf16x4*)&xb[i] = o;
}

// ---------------------------------------------------------------------------
// R21: W (fp32) -> bf16, 4 matrices (q,k,v,o) into contiguous Wb.
// Grid (576, 4): 589824 elems per matrix / 1024 per block.
// ---------------------------------------------------------------------------
__global__ __launch_bounds__(256)
void cvt_w_kernel(const float* __restrict__ Wq, const float* __restrict__ Wk,
                  const float* __restrict__ Wv, const float* __restrict__ Wo,
                  bf16* __restrict__ Wb) {
  const int m = blockIdx.y;
  const float* src = (m == 0) ? Wq : (m == 1) ? Wk : (m == 2) ? Wv : Wo;
  const int i = (blockIdx.x * 256 + threadIdx.x) * 4;
  float4 v = *(const float4*)&src[i];
  bf16x4 o;
  o[0] = (bf16)v.x; o[1] = (bf16)v.y; o[2] = (bf16)v.z; o[3] = (bf16)v.w;
  *(bf16x4*)&Wb[(size_t)m * 589824 + i] = o;
}

// ---------------------------------------------------------------------------
// Shared epilogue for QKV: write Q row-major / K,V in attn staging tiles
// (R15-R19 proven 6144-B tile layout):
//   K: [b][h][kt][u=d/8][k32][d%8]   V: [b][h][kt][ku=k/8][d96][k%8]
// ---------------------------------------------------------------------------
__device__ __forceinline__ void qkv_epilogue(
    int sel, int cb0, int rb0, int wc, int wr, int l15, int q4,
    const float* bia, fx4 (&acc)[4][4],
    bf16* Qo, bf16* Ka, bf16* Va) {
  const int cb = cb0 + wc * 64;
  const int rb = rb0 + wr * 64;
#pragma unroll
  for (int j = 0; j < 4; j++) {
    const int o  = cb + j * 16 + l15;
    const float bj = bia[o];
    const int hh = o / 96;
    const int dd = o - hh * 96;
#pragma unroll
    for (int i = 0; i < 4; i++) {
      const int r0 = rb + i * 16 + q4 * 4;
      if (sel == 2) {
        const int bb = r0 >> 11;
        const int n2 = r0 & 2047;
        const size_t flat =
            ((size_t)((bb * 8 + hh) * 64 + (n2 >> 5))) * 3072 +
            ((n2 >> 3) & 3) * 768 + dd * 8 + (n2 & 7);
        bf16x4 pk;
#pragma unroll
        for (int r = 0; r < 4; r++) pk[r] = (bf16)(acc[i][j][r] + bj);
        *(bf16x4*)&Va[flat] = pk;
      } else if (sel == 1) {
        const int u  = dd >> 3;
        const int de = dd & 7;
#pragma unroll
        for (int r = 0; r < 4; r++) {
          const int n  = r0 + r;
          const int bb = n >> 11;
          const int n2 = n & 2047;
          const size_t flat =
              ((size_t)((bb * 8 + hh) * 64 + (n2 >> 5))) * 3072 +
              u * 256 + (n2 & 31) * 8 + de;
          Ka[flat] = (bf16)(acc[i][j][r] + bj);
        }
      } else {
#pragma unroll
        for (int r = 0; r < 4; r++)
          Qo[(size_t)(r0 + r) * 768 + o] = (bf16)(acc[i][j][r] + bj);
      }
    }
  }
}

// ---------------------------------------------------------------------------
// R21 FAST PATH: fused QKV GEMM, A AND B both staged via global_load_lds
// DMA, double-buffered (m97 structure + counted vmcnt):
//   per k-step/wave: 4 DMA (next tile) -> wait vm4 (current landed) ->
//   barrier_nodrain -> 8 ds_read_b128 -> 16 MFMA -> barrier_nodrain.
// Requires Wb (bf16 weights) — host enables only if ws_size fits it.
// LDS 32 KB (As+Bs dbuf). No fp32 cvt chain in the loop.
// ---------------------------------------------------------------------------
__global__ __launch_bounds__(256)
void gemm_qkv_bf(const bf16* __restrict__ A, const bf16* __restrict__ Wb,
                 const float* __restrict__ bq, const float* __restrict__ bk,
                 const float* __restrict__ bv,
                 bf16* __restrict__ Qo, bf16* __restrict__ Ka,
                 bf16* __restrict__ Va) {
  constexpr int K = 768;
  __shared__ __align__(16) bf16 As[2][128 * 32];
  __shared__ __align__(16) bf16 Bs[2][128 * 32];

  const int tid  = threadIdx.x;
  const int wave = tid >> 6;
  const int lane = tid & 63;
  const int l15  = lane & 15;
  const int q4   = lane >> 4;
  const int wr   = wave >> 1;
  const int wc   = wave & 1;
  const int sel  = blockIdx.x / 6;
  const int cb0  = (blockIdx.x % 6) * 128;
  const int rb0  = blockIdx.y * 128;

  const bf16*  W   = Wb + (size_t)sel * 589824;
  const float* bia = (sel == 0) ? bq : (sel == 1) ? bk : bv;

  // Per-thread staging coords: row = tid>>2 (+64), kc = (tid&3)*8.
  // LDS dest offset = tid*8 elems (linear in tid) -> wave-linear DMA dest.
  const int ar0 = tid >> 2,  akc0 = (tid & 3) << 3;
  const int ar1 = ar0 + 64;

  fx4 acc[4][4];
#pragma unroll
  for (int i = 0; i < 4; i++)
#pragma unroll
    for (int j = 0; j < 4; j++) acc[i][j] = (fx4){0.f, 0.f, 0.f, 0.f};

  auto stage = [&](int k0, int buf) {
    gload_lds16(&A[(size_t)(rb0 + ar0) * K + k0 + akc0], &As[buf][wave * 512]);
    gload_lds16(&A[(size_t)(rb0 + ar1) * K + k0 + akc0],
                &As[buf][(wave + 4) * 512]);
    gload_lds16(&W[(size_t)(cb0 + ar0) * K + k0 + akc0], &Bs[buf][wave * 512]);
    gload_lds16(&W[(size_t)(cb0 + ar1) * K + k0 + akc0],
                &Bs[buf][(wave + 4) * 512]);
  };

  stage(0, 0);
  int cur = 0;
  for (int k0 = 0; k0 < K; k0 += 32, cur ^= 1) {
    const int kn = (k0 + 32 < K) ? k0 + 32 : k0;  // last iter: harmless redo
    stage(kn, cur ^ 1);
    wait_vm4();          // current tile's 4 (older) landed; next 4 in flight
    barrier_nodrain();

    bf16x8 a[4], b[4];
#pragma unroll
    for (int i = 0; i < 4; i++)
      a[i] = *(const bf16x8*)&As[cur][(wr * 64 + i * 16 + l15) * 32 + q4 * 8];
#pragma unroll
    for (int j = 0; j < 4; j++)
      b[j] = *(const bf16x8*)&Bs[cur][(wc * 64 + j * 16 + l15) * 32 + q4 * 8];
#pragma unroll
    for (int i = 0; i < 4; i++)
#pragma unroll
      for (int j = 0; j < 4; j++)
        acc[i][j] = MFMA16(a[i], b[j], acc[i][j]);

    barrier_nodrain();   // own ds_reads retired before next DMA overwrites
  }
  __builtin_amdgcn_s_waitcnt(0x0070);  // drain redundant tail DMA

  qkv_epilogue(sel, cb0, rb0, wc, wr, l15, q4, bia, acc, Qo, Ka, Va);
}

// ---------------------------------------------------------------------------
// R21 FAST PATH: output projection with full-DMA staging (same structure).
// ---------------------------------------------------------------------------
__global__ __launch_bounds__(256)
void gemm_o_bf(const bf16* __restrict__ A, const bf16* __restrict__ W,
               const float* __restrict__ bias, float* __restrict__ C) {
  constexpr int K = 768;
  __shared__ __align__(16) bf16 As[2][128 * 32];
  __shared__ __align__(16) bf16 Bs[2][128 * 32];

  const int tid  = threadIdx.x;
  const int wave = tid >> 6;
  const int lane = tid & 63;
  const int l15  = lane & 15;
  const int q4   = lane >> 4;
  const int wr   = wave >> 1;
  const int wc   = wave & 1;
  const int rb0  = blockIdx.y * 128;
  const int cb0  = blockIdx.x * 128;

  const int ar0 = tid >> 2,  akc0 = (tid & 3) << 3;
  const int ar1 = ar0 + 64;

  fx4 acc[4][4];
#pragma unroll
  for (int i = 0; i < 4; i++)
#pragma unroll
    for (int j = 0; j < 4; j++) acc[i][j] = (fx4){0.f, 0.f, 0.f, 0.f};

  auto stage = [&](int k0, int buf) {
    gload_lds16(&A[(size_t)(rb0 + ar0) * K + k0 + akc0], &As[buf][wave * 512]);
    gload_lds16(&A[(size_t)(rb0 + ar1) * K + k0 + akc0],
                &As[buf][(wave + 4) * 512]);
    gload_lds16(&W[(size_t)(cb0 + ar0) * K + k0 + akc0], &Bs[buf][wave * 512]);
    gload_lds16(&W[(size_t)(cb0 + ar1) * K + k0 + akc0],
                &Bs[buf][(wave + 4) * 512]);
  };

  stage(0, 0);
  int cur = 0;
  for (int k0 = 0; k0 < K; k0 += 32, cur ^= 1) {
    const int kn = (k0 + 32 < K) ? k0 + 32 : k0;
    stage(kn, cur ^ 1);
    wait_vm4();
    barrier_nodrain();

    bf16x8 a[4], b[4];
#pragma unroll
    for (int i = 0; i < 4; i++)
      a[i] = *(const bf16x8*)&As[cur][(wr * 64 + i * 16 + l15) * 32 + q4 * 8];
#pragma unroll
    for (int j = 0; j < 4; j++)
      b[j] = *(const bf16x8*)&Bs[cur][(wc * 64 + j * 16 + l15) * 32 + q4 * 8];
#pragma unroll
    for (int i = 0; i < 4; i++)
#pragma unroll
      for (int j = 0; j < 4; j++)
        acc[i][j] = MFMA16(a[i], b[j], acc[i][j]);

    barrier_nodrain();
  }
  __builtin_amdgcn_s_waitcnt(0x0070);

  const int cb = cb0 + wc * 64;
  const int rb = rb0 + wr * 64;
#pragma unroll
  for (int j = 0; j < 4; j++) {
    const int o  = cb + j * 16 + l15;
    const float bj = bias[o];
#pragma unroll
    for (int i = 0; i < 4; i++) {
      const int r0 = rb + i * 16 + q4 * 4;
#pragma unroll
      for (int r = 0; r < 4; r++)
        C[(size_t)(r0 + r) * 768 + o] = acc[i][j][r] + bj;
    }
  }
}

// ---------------------------------------------------------------------------
// FALLBACK (R17, proven): A DMA dbuf, B coalesced fp32-cvt staging.
// Used when ws_size can't hold bf16 weights.
// ---------------------------------------------------------------------------
__global__ __launch_bounds__(256)
void gemm_qkv(const bf16* __restrict__ A,
              const float* __restrict__ Wq, const float* __restrict__ Wk,
              const float* __restrict__ Wv,
              const float* __restrict__ bq, const float* __restrict__ bk,
              const float* __restrict__ bv,
              bf16* __restrict__ Qo, bf16* __restrict__ Ka,
              bf16* __restrict__ Va) {
  constexpr int K = 768;
  __shared__ __align__(16) bf16 As[2][128 * 32];
  __shared__ __align__(16) bf16 Bs[128 * 32];

  const int tid  = threadIdx.x;
  const int wave = tid >> 6;
  const int lane = tid & 63;
  const int l15  = lane & 15;
  const int q4   = lane >> 4;
  const int wr   = wave >> 1;
  const int wc   = wave & 1;
  const int sel  = blockIdx.x / 6;
  const int cb0  = (blockIdx.x % 6) * 128;
  const int rb0  = blockIdx.y * 128;

  const float* W   = (sel == 0) ? Wq : (sel == 1) ? Wk : Wv;
  const float* bia = (sel == 0) ? bq : (sel == 1) ? bk : bv;

  const int ar0 = tid >> 2,  akc0 = (tid & 3) << 3;
  const int ar1 = ar0 + 64;

  fx4 acc[4][4];
#pragma unroll
  for (int i = 0; i < 4; i++)
#pragma unroll
    for (int j = 0; j < 4; j++) acc[i][j] = (fx4){0.f, 0.f, 0.f, 0.f};

  gload_lds16(&A[(size_t)(rb0 + ar0) * K + akc0], &As[0][wave * 512]);
  gload_lds16(&A[(size_t)(rb0 + ar1) * K + akc0], &As[0][(wave + 4) * 512]);

  int cur = 0;
  for (int k0 = 0; k0 < K; k0 += 32, cur ^= 1) {
    const float* wp0 = W + (size_t)(cb0 + ar0) * K + k0 + akc0;
    const float* wp1 = W + (size_t)(cb0 + ar1) * K + k0 + akc0;
    const float4 b0a = *(const float4*)wp0;
    const float4 b0b = *(const float4*)(wp0 + 4);
    const float4 b1a = *(const float4*)wp1;
    const float4 b1b = *(const float4*)(wp1 + 4);
    __asm__ __volatile__("" ::: "memory");

    const int kn = (k0 + 32 < K) ? k0 + 32 : k0;
    gload_lds16(&A[(size_t)(rb0 + ar0) * K + kn + akc0],
                &As[cur ^ 1][wave * 512]);
    gload_lds16(&A[(size_t)(rb0 + ar1) * K + kn + akc0],
                &As[cur ^ 1][(wave + 4) * 512]);
    __asm__ __volatile__("" ::: "memory");

    bf16x8 pb0, pb1;
    pb0[0] = (bf16)b0a.x; pb0[1] = (bf16)b0a.y;
    pb0[2] = (bf16)b0a.z; pb0[3] = (bf16)b0a.w;
    pb0[4] = (bf16)b0b.x; pb0[5] = (bf16)b0b.y;
    pb0[6] = (bf16)b0b.z; pb0[7] = (bf16)b0b.w;
    pb1[0] = (bf16)b1a.x; pb1[1] = (bf16)b1a.y;
    pb1[2] = (bf16)b1a.z; pb1[3] = (bf16)b1a.w;
    pb1[4] = (bf16)b1b.x; pb1[5] = (bf16)b1b.y;
    pb1[6] = (bf16)b1b.z; pb1[7] = (bf16)b1b.w;
    *(bf16x8*)&Bs[ar0 * 32 + akc0] = pb0;
    *(bf16x8*)&Bs[ar1 * 32 + akc0] = pb1;

    barrier_nodrain();

    bf16x8 a[4], b[4];
#pragma unroll
    for (int i = 0; i < 4; i++)
      a[i] = *(const bf16x8*)&As[cur][(wr * 64 + i * 16 + l15) * 32 + q4 * 8];
#pragma unroll
    for (int j = 0; j < 4; j++)
      b[j] = *(const bf16x8*)&Bs[(wc * 64 + j * 16 + l15) * 32 + q4 * 8];
#pragma unroll
    for (int i = 0; i < 4; i++)
#pragma unroll
      for (int j = 0; j < 4; j++)
        acc[i][j] = MFMA16(a[i], b[j], acc[i][j]);

    barrier_nodrain();
  }

  qkv_epilogue(sel, cb0, rb0, wc, wr, l15, q4, bia, acc, Qo, Ka, Va);
}

__global__ __launch_bounds__(256)
void gemm_o(const bf16* __restrict__ A, const float* __restrict__ W,
            const float* __restrict__ bias, float* __restrict__ C) {
  constexpr int K = 768;
  __shared__ __align__(16) bf16 As[2][128 * 32];
  __shared__ __align__(16) bf16 Bs[128 * 32];

  const int tid  = threadIdx.x;
  const int wave = tid >> 6;
  const int lane = tid & 63;
  const int l15  = lane & 15;
  const int q4   = lane >> 4;
  const int wr   = wave >> 1;
  const int wc   = wave & 1;
  const int rb0  = blockIdx.y * 128;
  const int cb0  = blockIdx.x * 128;

  const int ar0 = tid >> 2,  akc0 = (tid & 3) << 3;
  const int ar1 = ar0 + 64;

  fx4 acc[4][4];
#pragma unroll
  for (int i = 0; i < 4; i++)
#pragma unroll
    for (int j = 0; j < 4; j++) acc[i][j] = (fx4){0.f, 0.f, 0.f, 0.f};

  gload_lds16(&A[(size_t)(rb0 + ar0) * K + akc0], &As[0][wave * 512]);
  gload_lds16(&A[(size_t)(rb0 + ar1) * K + akc0], &As[0][(wave + 4) * 512]);

  int cur = 0;
  for (int k0 = 0; k0 < K; k0 += 32, cur ^= 1) {
    const float* wp0 = W + (size_t)(cb0 + ar0) * K + k0 + akc0;
    const float* wp1 = W + (size_t)(cb0 + ar1) * K + k0 + akc0;
    const float4 b0a = *(const float4*)wp0;
    const float4 b0b = *(const float4*)(wp0 + 4);
    const float4 b1a = *(const float4*)wp1;
    const float4 b1b = *(const float4*)(wp1 + 4);
    __asm__ __volatile__("" ::: "memory");

    const int kn = (k0 + 32 < K) ? k0 + 32 : k0;
    gload_lds16(&A[(size_t)(rb0 + ar0) * K + kn + akc0],
                &As[cur ^ 1][wave * 512]);
    gload_lds16(&A[(size_t)(rb0 + ar1) * K + kn + akc0],
                &As[cur ^ 1][(wave + 4) * 512]);
    __asm__ __volatile__("" ::: "memory");

    bf16x8 pb0, pb1;
    pb0[0] = (bf16)b0a.x; pb0[1] = (bf16)b0a.y;
    pb0[2] = (bf16)b0a.z; pb0[3] = (bf16)b0a.w;
    pb0[4] = (bf16)b0b.x; pb0[5] = (bf16)b0b.y;
    pb0[6] = (bf16)b0b.z; pb0[7] = (bf16)b0b.w;
    pb1[0] = (bf16)b1a.x; pb1[1] = (bf16)b1a.y;
    pb1[2] = (bf16)b1a.z; pb1[3] = (bf16)b1a.w;
    pb1[4] = (bf16)b1b.x; pb1[5] = (bf16)b1b.y;
    pb1[6] = (bf16)b1b.z; pb1[7] = (bf16)b1b.w;
    *(bf16x8*)&Bs[ar0 * 32 + akc0] = pb0;
    *(bf16x8*)&Bs[ar1 * 32 + akc0] = pb1;

    barrier_nodrain();

    bf16x8 a[4], b[4];
#pragma unroll
    for (int i = 0; i < 4; i++)
      a[i] = *(const bf16x8*)&As[cur][(wr * 64 + i * 16 + l15) * 32 + q4 * 8];
#pragma unroll
    for (int j = 0; j < 4; j++)
      b[j] = *(const bf16x8*)&Bs[(wc * 64 + j * 16 + l15) * 32 + q4 * 8];
#pragma unroll
    for (int i = 0; i < 4; i++)
#pragma unroll
      for (int j = 0; j < 4; j++)
        acc[i][j] = MFMA16(a[i], b[j], acc[i][j]);

    barrier_nodrain();
  }

  const int cb = cb0 + wc * 64;
  const int rb = rb0 + wr * 64;
#pragma unroll
  for (int j = 0; j < 4; j++) {
    const int o  = cb + j * 16 + l15;
    const float bj = bias[o];
#pragma unroll
    for (int i = 0; i < 4; i++) {
      const int r0 = rb + i * 16 + q4 * 4;
#pragma unroll
      for (int r = 0; r < 4; r++)
        C[(size_t)(r0 + r) * 768 + o] = acc[i][j][r] + bj;
    }
  }
}

// ---------------------------------------------------------------------------
// Attention (R19, proven 139.8 µs — reverted from R20's regression; the
// smaller-tile 2-block/CU variant doubled per-iteration overhead + bank
// conflicts 3.1M->9.4M and lost 61% despite 40% occupancy).
// Softmax over HEADS (dim=1), / sqrt(768). Swapped QK^T (E^T), vectorized
// scatter (b128), k-pair softmax (b64), bf16 Pbuf. DMA K/V staging,
// counted vm6, nodrain barriers.
// LDS: 48 + 48 + 32.5 + 20 = 148.5 KB (1 block/CU).
// ---------------------------------------------------------------------------
__global__ __launch_bounds__(512, 1)
void attn_kernel(const bf16* Q, const bf16* __restrict__ Ka,
                 const bf16* __restrict__ Va, bf16* AO) {
  __shared__ __align__(16) bf16  Kbuf[8 * 3072];   // [h][u12][k32][8] 48 KB
  __shared__ __align__(16) bf16  Vbuf[8 * 3072];   // [h][ku4][d96][8] 48 KB
  __shared__ __align__(16) float Ebuf[32 * 260];   // [q][h*32+k]    32.5 KB
  __shared__ __align__(16) bf16  Pbuf[8 * 32 * 40]; // [h][q][k pad40] 20 KB

  const int tid  = threadIdx.x;
  const int h    = tid >> 6;
  const int lane = tid & 63;
  const int l15  = lane & 15;
  const int q4   = lane >> 4;
  const int b    = blockIdx.x >> 6;
  const int qt   = blockIdx.x & 63;
  const int qrow0 = b * 2048 + qt * 32;

  bf16x8 aq[2][3];
#pragma unroll
  for (int i = 0; i < 2; i++)
#pragma unroll
    for (int c = 0; c < 3; c++)
      aq[i][c] = *(const bf16x8*)
          &Q[(size_t)(qrow0 + i * 16 + l15) * 768 + h * 96 + c * 32 + q4 * 8];

  fx4 o[2][6];
#pragma unroll
  for (int i = 0; i < 2; i++)
#pragma unroll
    for (int j = 0; j < 6; j++) o[i][j] = (fx4){0.f, 0.f, 0.f, 0.f};

  const bf16* Kt0 = Ka + (size_t)(b * 8 + h) * 64 * 3072;
  const bf16* Vt0 = Va + (size_t)(b * 8 + h) * 64 * 3072;
  bf16* Kl = &Kbuf[h * 3072];
  bf16* Vl = &Vbuf[h * 3072];

  auto stageK = [&](int kt) {
    const bf16* src = Kt0 + (size_t)kt * 3072 + lane * 8;
#pragma unroll
    for (int t = 0; t < 6; t++)
      gload_lds16(src + t * 512, Kl + t * 512);
  };
  auto stageV = [&](int kt) {
    const bf16* src = Vt0 + (size_t)kt * 3072 + lane * 8;
#pragma unroll
    for (int t = 0; t < 6; t++)
      gload_lds16(src + t * 512, Vl + t * 512);
  };

  stageK(0);
  stageV(0);

  for (int kt = 0; kt < 64; kt++) {
    const int kn = (kt + 1 < 64) ? kt + 1 : 63;

    wait_vm6();

    bf16x8 bk[2][3];
#pragma unroll
    for (int j = 0; j < 2; j++)
#pragma unroll
      for (int c = 0; c < 3; c++)
        bk[j][c] =
            *(const bf16x8*)&Kl[(c * 4 + q4) * 256 + (j * 16 + l15) * 8];

    wait_lgkm0();
    stageK(kn);

    // E^T = K Q^T (swapped): lane owns q = i*16+l15, k = j*16+q4*4+r.
    fx4 e2[2][2];
    e2[0][0] = e2[0][1] = e2[1][0] = e2[1][1] = (fx4){0.f, 0.f, 0.f, 0.f};
    __builtin_amdgcn_s_setprio(1);
#pragma unroll
    for (int c = 0; c < 3; c++)
#pragma unroll
      for (int j = 0; j < 2; j++) {
        e2[j][0] = MFMA16(bk[j][c], aq[0][c], e2[j][0]);
        e2[j][1] = MFMA16(bk[j][c], aq[1][c], e2[j][1]);
      }
    __builtin_amdgcn_s_setprio(0);

#pragma unroll
    for (int i = 0; i < 2; i++)
#pragma unroll
      for (int j = 0; j < 2; j++)
        *(fx4*)&Ebuf[(i * 16 + l15) * 260 + h * 32 + j * 16 + q4 * 4] =
            e2[j][i];
    barrier_nodrain();

    // Softmax over heads, (q, 2 adjacent k) per thread.
    {
      const int q  = tid >> 4;
      const int k2 = (tid & 15) << 1;
      const float* row = &Ebuf[q * 260 + k2];
      fx2 v[8];
#pragma unroll
      for (int hh = 0; hh < 8; hh++) v[hh] = *(const fx2*)&row[hh * 32];
      fx2 m = v[0];
#pragma unroll
      for (int hh = 1; hh < 8; hh++) {
        m[0] = fmaxf(m[0], v[hh][0]);
        m[1] = fmaxf(m[1], v[hh][1]);
      }
      fx2 sm = (fx2){0.f, 0.f};
#pragma unroll
      for (int hh = 0; hh < 8; hh++) {
        v[hh][0] = __expf(v[hh][0] - m[0]);
        v[hh][1] = __expf(v[hh][1] - m[1]);
        sm += v[hh];
      }
      const float inv0 = 1.0f / (sm[0] * 27.712812921102035f);  // / sqrt(768)
      const float inv1 = 1.0f / (sm[1] * 27.712812921102035f);
#pragma unroll
      for (int hh = 0; hh < 8; hh++) {
        bf16x2 pk;
        pk[0] = (bf16)(v[hh][0] * inv0);
        pk[1] = (bf16)(v[hh][1] * inv1);
        *(bf16x2*)&Pbuf[hh * 1280 + q * 40 + k2] = pk;
      }
    }
    barrier_nodrain();

    wait_vm6();

    bf16x8 bv[6];
#pragma unroll
    for (int j2 = 0; j2 < 6; j2++)
      bv[j2] = *(const bf16x8*)&Vl[q4 * 768 + (j2 * 16 + l15) * 8];

    bf16x8 ap[2];
#pragma unroll
    for (int i = 0; i < 2; i++)
      ap[i] = *(const bf16x8*)&Pbuf[h * 1280 + (i * 16 + l15) * 40 + q4 * 8];

    wait_lgkm0();
    stageV(kn);

    __builtin_amdgcn_s_setprio(1);
#pragma unroll
    for (int j2 = 0; j2 < 6; j2++) {
      o[0][j2] = MFMA16(ap[0], bv[j2], o[0][j2]);
      o[1][j2] = MFMA16(ap[1], bv[j2], o[1][j2]);
    }
    __builtin_amdgcn_s_setprio(0);
  }

  __builtin_amdgcn_s_waitcnt(0x0070);

#pragma unroll
  for (int i = 0; i < 2; i++)
#pragma unroll
    for (int j2 = 0; j2 < 6; j2++)
#pragma unroll
      for (int r = 0; r < 4; r++)
        AO[(size_t)(qrow0 + i * 16 + q4 * 4 + r) * 768 + h * 96 + j2 * 16 + l15] =
            (bf16)(o[i][j2][r]);
}

// ---------------------------------------------------------------------------
// Memory plan: d_out = xb + Ka. ws = Q + Va (+ Wb bf16 weights when
// ws_size >= 29,884,416 B — host-side runtime check; else R17 fallback
// GEMMs that convert W in the staging loop). AO aliases Q.
// ---------------------------------------------------------------------------
extern "C" void kernel_launch(void* const* d_in, const int* in_sizes, int n_in,
                              void* d_out, int out_size, void* d_ws,
                              size_t ws_size, hipStream_t stream) {
  const float* x  = (const float*)d_in[0];
  const float* Wq = (const float*)d_in[1];
  const float* bq = (const float*)d_in[2];
  const float* Wk = (const float*)d_in[3];
  const float* bk = (const float*)d_in[4];
  const float* Wv = (const float*)d_in[5];
  const float* bv = (const float*)d_in[6];
  const float* Wo = (const float*)d_in[7];
  const float* bo = (const float*)d_in[8];

  const size_t MN = (size_t)8192 * 768;
  bf16* xb = (bf16*)d_out;
  bf16* Ka = xb + MN;
  bf16* Q  = (bf16*)d_ws;
  bf16* Va = Q + MN;
  bf16* AO = Q;  // aliases Q

  const size_t need_fast = MN * 2 * 2 + (size_t)4 * 589824 * 2;  // 29,884,416
  const bool fast = ws_size >= need_fast;
  bf16* Wb = Va + MN;  // tail of ws (only touched in fast path)

  cvt_x_kernel<<<6144, 256, 0, stream>>>(x, xb);
  if (fast) {
    dim3 wgrid(576, 4);
    cvt_w_kernel<<<wgrid, 256, 0, stream>>>(Wq, Wk, Wv, Wo, Wb);
    dim3 qkvgrid(18, 64);
    gemm_qkv_bf<<<qkvgrid, 256, 0, stream>>>(xb, Wb, bq, bk, bv, Q, Ka, Va);
  } else {
    dim3 qkvgrid(18, 64);
    gemm_qkv<<<qkvgrid, 256, 0, stream>>>(xb, Wq, Wk, Wv, bq, bk, bv,
                                          Q, Ka, Va);
  }
  attn_kernel<<<256, 512, 0, stream>>>(Q, Ka, Va, AO);
  dim3 ogrid(6, 64);
  if (fast) {
    gemm_o_bf<<<ogrid, 256, 0, stream>>>(AO, Wb + (size_t)3 * 589824, bo,
                                         (float*)d_out);
  } else {
    gemm_o<<<ogrid, 256, 0, stream>>>(AO, Wo, bo, (float*)d_out);
  }
}